// Round 7
// baseline (154.805 us; speedup 1.0000x reference)
//
#include <hip/hip_runtime.h>
#include <stdint.h>

typedef unsigned long long u64;

#define CC 256
#define HH 28
#define WW 28
#define PP 784          // H*W
#define NHW 25088       // N*H*W
#define WPO 36          // 9 taps * 4 u64 words per output channel

// ---------------------------------------------------------------------------
// prep: pack_x (lane=pixel, coalesced) + pack both weight tensors + per-o
// edge-correction tables D[o][16] + zero stats. grid 2176 x 64 threads.
// D(o,e) = 2*sum_{pad taps}popc(w) - 256*npad, so that for a zero-padded
// input window: dot = 2304 - 2*acc_all + D(o, edgetype).
// ---------------------------------------------------------------------------
__global__ __launch_bounds__(64) void prep(const float* __restrict__ x,
        const float* __restrict__ w1, const float* __restrict__ w2,
        u64* __restrict__ xp, u64* __restrict__ wp1, u64* __restrict__ wp2,
        int* __restrict__ dt1, int* __restrict__ dt2,
        int* s1i, double* s1q, double* s2s, double* s2q) {
    int bx = blockIdx.x, lane = threadIdx.x;
    if (bx < 1664) {                     // 32 n * 4 g * 13 ptiles
        int n = bx / 52, rem = bx % 52, g = rem / 13, pt = rem % 13;
        int p = pt * 64 + lane;
        if (p < PP) {
            const float* base = x + ((size_t)n * CC + g * 64) * PP + p;
            u64 w = 0;
#pragma unroll 8
            for (int cb = 0; cb < 64; ++cb)
                if (base[(size_t)cb * PP] > 0.0f) w |= (1ull << cb);
            xp[((size_t)n * PP + p) * 4 + g] = w;
        }
    } else {
        int u = bx - 1664, which = u >> 8, o = u & 255;
        if (u < 4) {                     // fold in stats zeroing
            s1i[u * 64 + lane] = 0; s1q[u * 64 + lane] = 0.0;
            s2s[u * 64 + lane] = 0.0; s2q[u * 64 + lane] = 0.0;
        }
        const float* w = which ? w2 : w1;
        u64* wp = which ? wp2 : wp1;
        int* dt = which ? dt2 : dt1;
        __shared__ u64 wsm[36];
#pragma unroll
        for (int cg = 0; cg < 4; ++cg)
            for (int tap = 0; tap < 9; ++tap) {
                u64 m = __ballot(w[((size_t)o * CC + cg * 64 + lane) * 9 + tap] > 0.0f);
                if (lane == 0) { wp[(size_t)o * WPO + tap * 4 + cg] = m; wsm[tap * 4 + cg] = m; }
            }
        __syncthreads();
        if (lane == 0) {
            int tp[9];
#pragma unroll
            for (int t = 0; t < 9; ++t)
                tp[t] = (int)__popcll(wsm[t*4]) + (int)__popcll(wsm[t*4+1])
                      + (int)__popcll(wsm[t*4+2]) + (int)__popcll(wsm[t*4+3]);
            for (int e = 0; e < 16; ++e) {
                int C = 0, np = 0;
                for (int t = 0; t < 9; ++t) {
                    int tr = t / 3, tc = t % 3;
                    bool pad = ((e & 1) && tr == 0) || ((e & 2) && tr == 2)
                            || ((e & 4) && tc == 0) || ((e & 8) && tc == 2);
                    if (pad) { C += tp[t]; np++; }
                }
                dt[o * 16 + e] = 2 * C - 256 * np;
            }
        }
    }
}

// ---------------------------------------------------------------------------
// binconv: lane = pixel, loop over 32 output channels. grid (13 pt, 8 og, 32 n),
// block 64 (1 wave). Inputs: 36 u64 per-lane window in VGPRs (loaded once from
// zero-padded LDS tile). Weights: wave-uniform -> SGPRs via s_load, XOR'd as
// the scalar operand. Edge handling branch-free via D table (LDS, 2KB).
// Output v in NCHW int16 (coalesced 128B store per o).
// NOTE: a 64-pixel tile can span FOUR rows of W=28 (when p0%28 >= 21), so the
// padded LDS tile needs 6 rows (rf-1 .. rf+4). 5 rows overflowed -> round-6 bug.
// ---------------------------------------------------------------------------
__global__ __attribute__((amdgpu_flat_work_group_size(64, 64), amdgpu_waves_per_eu(4, 4)))
void binconv(const u64* __restrict__ xp, const u64* __restrict__ wp,
             const int* __restrict__ dtab, short* __restrict__ vout) {
    __shared__ u64 lin[6][30][4];        // zero-padded: 6 rows x (1+28+1) cols x 4 words
    __shared__ int dl[512];              // D[o in og-range][16]
    int lane = threadIdx.x;
    int pt = blockIdx.x, og = blockIdx.y, n = blockIdx.z;
    int p0 = pt * 64;
    int rf = p0 / 28;
    int rl = (p0 + 63) / 28; if (rl > 27) rl = 27;

    for (int i = lane; i < 720; i += 64) ((u64*)lin)[i] = 0;
    __syncthreads();
    int nrows = rl - rf + 3;             // staged rows rf-1 .. rl+1 (<=6)
    for (int idx = lane; idx < nrows * 56; idx += 64) {
        int row = idx / 56, off = idx % 56;   // off in ulonglong2 units
        int gr = rf - 1 + row;
        if (gr >= 0 && gr < HH) {
            ulonglong2 t = *(const ulonglong2*)(xp + ((size_t)n * PP + gr * WW) * 4 + off * 2);
            *(ulonglong2*)((u64*)lin + (size_t)row * 120 + 4 + off * 2) = t;
        }
    }
    for (int j = lane; j < 512; j += 64) dl[j] = dtab[og * 512 + j];
    __syncthreads();

    int p = p0 + lane;
    bool st = (p < PP);
    int pc = st ? p : (PP - 1);
    int r = pc / 28, c = pc % 28;
    int lrow = r - rf + 1;

    u64 win[36];
#pragma unroll
    for (int dr = 0; dr < 3; ++dr)
#pragma unroll
        for (int dc = 0; dc < 3; ++dc) {
            const u64* q = &lin[lrow - 1 + dr][c + dc][0];
            ulonglong2 q0 = *(const ulonglong2*)q;
            ulonglong2 q1 = *(const ulonglong2*)(q + 2);
            int t = (dr * 3 + dc) * 4;
            win[t] = q0.x; win[t + 1] = q0.y; win[t + 2] = q1.x; win[t + 3] = q1.y;
        }
    int eidx = (r == 0 ? 1 : 0) | (r == 27 ? 2 : 0) | (c == 0 ? 4 : 0) | (c == 27 ? 8 : 0);

    short* vp = vout + ((size_t)n * CC + og * 32) * PP + p;
#pragma unroll 1
    for (int i = 0; i < 32; ++i) {
        const u64* wo = wp + (size_t)(og * 32 + i) * WPO;   // wave-uniform -> s_load
        int a0 = 0, a1 = 0, a2 = 0, a3 = 0;
#pragma unroll
        for (int t = 0; t < 9; ++t) {
            a0 += (int)__popcll(win[t*4+0] ^ wo[t*4+0]);
            a1 += (int)__popcll(win[t*4+1] ^ wo[t*4+1]);
            a2 += (int)__popcll(win[t*4+2] ^ wo[t*4+2]);
            a3 += (int)__popcll(win[t*4+3] ^ wo[t*4+3]);
        }
        int dot = 2304 + dl[i * 16 + eidx] - 2 * (a0 + a1 + a2 + a3);
        if (st) *vp = (short)dot;
        vp += PP;
    }
}

// ---------------------------------------------------------------------------
// stats1: per-channel exact int stats of v1 (NCHW int16). grid (256, 4), 256 thr.
// Sum-of-squares kept exact: per-thread int32 (<2^31), block/global in f64 (<2^53).
// ---------------------------------------------------------------------------
__global__ __launch_bounds__(256) void stats1(const short* __restrict__ v1,
                                              int* __restrict__ s1i, double* __restrict__ s1q) {
    int o = blockIdx.x, nq = blockIdx.y, tid = threadIdx.x;
    int s = 0, q = 0;
    for (int nn = 0; nn < 8; ++nn) {
        const short* b = v1 + ((size_t)(nq * 8 + nn) * CC + o) * PP;
        for (int j = tid; j < PP; j += 256) { int v = b[j]; s += v; q += v * v; }
    }
    double qd = (double)q;
    for (int d = 32; d; d >>= 1) { s += __shfl_down(s, d, 64); qd += __shfl_down(qd, d, 64); }
    __shared__ int rs[4]; __shared__ double rq[4];
    int wid = tid >> 6;
    if ((tid & 63) == 0) { rs[wid] = s; rq[wid] = qd; }
    __syncthreads();
    if (tid == 0) {
        atomicAdd(&s1i[o], rs[0] + rs[1] + rs[2] + rs[3]);
        atomicAdd(&s1q[o], rq[0] + rq[1] + rq[2] + rq[3]);
    }
}

// ---------------------------------------------------------------------------
// repack: sign(BN1(v1)) -> bit-pack xp2 [n][p][4]. BN1 params inline (per-block).
// grid (13 pt, 32 n), 256 thr (wave g builds word g for 64 pixels).
// ---------------------------------------------------------------------------
__global__ __launch_bounds__(256) void repack(const short* __restrict__ v1,
        const int* __restrict__ s1i, const double* __restrict__ s1q,
        const float* __restrict__ gamma, const float* __restrict__ beta,
        u64* __restrict__ xp2) {
    __shared__ float ash[256], bsh[256];
    int pt = blockIdx.x, n = blockIdx.y, tid = threadIdx.x;
    {
        int cc = tid;
        double mean = (double)s1i[cc] * (1.0 / NHW);
        double msq  = s1q[cc] * (1.0 / NHW);
        double var  = msq - mean * mean;
        double istd = 1.0 / sqrt(var + 1e-5);
        double ad   = (double)gamma[cc] * istd;
        ash[cc] = (float)ad;
        bsh[cc] = (float)((double)beta[cc] - mean * ad);
    }
    __syncthreads();
    int g = tid >> 6, lane = tid & 63;
    int p = pt * 64 + lane;
    bool act = p < PP;
    int pcl = act ? p : PP - 1;
    u64 wbits = 0;
#pragma unroll 8
    for (int cb = 0; cb < 64; ++cb) {
        int cc = g * 64 + cb;
        int v = v1[((size_t)n * CC + cc) * PP + pcl];
        float y = fmaf(ash[cc], (float)v, bsh[cc]);
        if (y > 0.0f) wbits |= (1ull << cb);
    }
    if (act) xp2[((size_t)n * PP + p) * 4 + g] = wbits;
}

// ---------------------------------------------------------------------------
// stats2: per-channel f64 stats of (v2 + x). grid (256, 4), 256 thr.
// ---------------------------------------------------------------------------
__global__ __launch_bounds__(256) void stats2(const short* __restrict__ v2, const float* __restrict__ x,
                                              double* __restrict__ s2s, double* __restrict__ s2q) {
    int o = blockIdx.x, nq = blockIdx.y, tid = threadIdx.x;
    double sd = 0.0, qd = 0.0;
    for (int nn = 0; nn < 8; ++nn) {
        size_t base = ((size_t)(nq * 8 + nn) * CC + o) * PP;
        for (int j = tid; j < PP; j += 256) {
            float u = (float)v2[base + j] + x[base + j];
            sd += (double)u; qd += (double)u * (double)u;
        }
    }
    for (int d = 32; d; d >>= 1) { sd += __shfl_down(sd, d, 64); qd += __shfl_down(qd, d, 64); }
    __shared__ double rs[4], rq[4];
    int wid = tid >> 6;
    if ((tid & 63) == 0) { rs[wid] = sd; rq[wid] = qd; }
    __syncthreads();
    if (tid == 0) {
        atomicAdd(&s2s[o], rs[0] + rs[1] + rs[2] + rs[3]);
        atomicAdd(&s2q[o], rq[0] + rq[1] + rq[2] + rq[3]);
    }
}

// ---------------------------------------------------------------------------
// finalize: out = clip(sc*(v2 + x) + bi, -1, 1), pure elementwise (all NCHW).
// grid 6272 x 256 (vec4 per thread, exact cover of 6422528 elements).
// ---------------------------------------------------------------------------
__global__ __launch_bounds__(256) void finalize(const short* __restrict__ v2, const float* __restrict__ x,
        const double* __restrict__ s2s, const double* __restrict__ s2q,
        const float* __restrict__ gamma, const float* __restrict__ beta,
        float* __restrict__ out) {
    int i4 = blockIdx.x * 256 + threadIdx.x;
    size_t flat = (size_t)i4 * 4;
    int cc = (int)((flat / PP) & 255);          // vec4 never crosses a channel row
    double mean = s2s[cc] * (1.0 / NHW);
    double msq  = s2q[cc] * (1.0 / NHW);
    double var  = msq - mean * mean;
    double istd = 1.0 / sqrt(var + 1e-5);
    double ad   = (double)gamma[cc] * istd;
    float sc = (float)ad;
    float bi = (float)((double)beta[cc] - mean * ad);
    float4 xv = *(const float4*)(x + flat);
    short4 vv = *(const short4*)(v2 + flat);
    float4 ov;
    ov.x = fminf(fmaxf(fmaf(sc, (float)vv.x + xv.x, bi), -1.0f), 1.0f);
    ov.y = fminf(fmaxf(fmaf(sc, (float)vv.y + xv.y, bi), -1.0f), 1.0f);
    ov.z = fminf(fmaxf(fmaf(sc, (float)vv.z + xv.z, bi), -1.0f), 1.0f);
    ov.w = fminf(fmaxf(fmaf(sc, (float)vv.w + xv.w, bi), -1.0f), 1.0f);
    *(float4*)(out + flat) = ov;
}

// ---------------------------------------------------------------------------
extern "C" void kernel_launch(void* const* d_in, const int* in_sizes, int n_in,
                              void* d_out, int out_size, void* d_ws, size_t ws_size,
                              hipStream_t stream) {
    (void)in_sizes; (void)n_in; (void)out_size; (void)ws_size;
    const float* x   = (const float*)d_in[0];
    const float* w1  = (const float*)d_in[1];
    const float* g1  = (const float*)d_in[2];
    const float* b1  = (const float*)d_in[3];
    const float* w2  = (const float*)d_in[4];
    const float* g2  = (const float*)d_in[5];
    const float* b2  = (const float*)d_in[6];
    float* out = (float*)d_out;

    char* ws = (char*)d_ws;
    u64*    xp1 = (u64*)(ws + 0);            //   802816 B
    u64*    xp2 = (u64*)(ws + 802816);       //   802816 B
    u64*    wp1 = (u64*)(ws + 1605632);      //    73728 B
    u64*    wp2 = (u64*)(ws + 1679360);      //    73728 B
    int*    s1i = (int*)(ws + 1753088);      //     1024 B
    double* s1q = (double*)(ws + 1754112);   //     2048 B
    double* s2s = (double*)(ws + 1756160);   //     2048 B
    double* s2q = (double*)(ws + 1758208);   //     2048 B
    int*    dt1 = (int*)(ws + 1760256);      //    16384 B
    int*    dt2 = (int*)(ws + 1776640);      //    16384 B
    short*  v12 = (short*)(ws + 1793024);    // 12845056 B (v1, then reused as v2)

    prep<<<2176, 64, 0, stream>>>(x, w1, w2, xp1, wp1, wp2, dt1, dt2, s1i, s1q, s2s, s2q);
    binconv<<<dim3(13, 8, 32), 64, 0, stream>>>(xp1, wp1, dt1, v12);
    stats1<<<dim3(256, 4), 256, 0, stream>>>(v12, s1i, s1q);
    repack<<<dim3(13, 32), 256, 0, stream>>>(v12, s1i, s1q, g1, b1, xp2);
    binconv<<<dim3(13, 8, 32), 64, 0, stream>>>(xp2, wp2, dt2, v12);
    stats2<<<dim3(256, 4), 256, 0, stream>>>(v12, x, s2s, s2q);
    finalize<<<6272, 256, 0, stream>>>(v12, x, s2s, s2q, g2, b2, out);
}